// Round 6
// baseline (318.442 us; speedup 1.0000x reference)
//
#include <hip/hip_runtime.h>
#include <cstdint>
#include <cstddef>

#define INPUT_DIM 784
#define HIDDEN    4096
#define BATCH     64
#define T_STEPS   30
#define N0 (BATCH*INPUT_DIM)   // 50176
#define N1 (BATCH*HIDDEN)      // 262144
#define M_ROWS (T_STEPS*BATCH) // 1920
#define NDIG 4
#define MB_CNT (M_ROWS/32)     // 60
#define KC1 25                 // gemm1 k-chunks (784 padded to 800)
#define KC2 128                // gemm2 k-chunks

typedef int v4i  __attribute__((ext_vector_type(4)));
typedef int v16i __attribute__((ext_vector_type(16)));

// ---------------- max(x) reduction (unchanged, passing) --------------------
__global__ __launch_bounds__(256) void max_kernel(const float* __restrict__ x,
                                                  unsigned* __restrict__ maxbits) {
    int i = blockIdx.x * 256 + threadIdx.x;
    float v = (i < N0) ? x[i] : 0.0f;
    #pragma unroll
    for (int off = 32; off > 0; off >>= 1)
        v = fmaxf(v, __shfl_down(v, off, 64));
    __shared__ float sm[4];
    int lane = threadIdx.x & 63;
    int wv   = threadIdx.x >> 6;
    if (lane == 0) sm[wv] = v;
    __syncthreads();
    if (threadIdx.x == 0) {
        float m = fmaxf(fmaxf(sm[0], sm[1]), fmaxf(sm[2], sm[3]));
        atomicMax(maxbits, __float_as_uint(m));
    }
}

// ---------------- layer 0 LIF: same math (passing), spikes -> A-fragments --
// AF1[kc][mb][lane][16], lane=(b&31)|(((j>>4)&1)<<5), mb=2t+(b>>5), byte=j&15.
__global__ __launch_bounds__(256) void lif0_kernel(const float* __restrict__ x,
                                                   const unsigned* __restrict__ maxbits,
                                                   uint8_t* __restrict__ AF1,
                                                   float* __restrict__ out0) {
    int j = blockIdx.x * 256 + threadIdx.x;   // input-dim index
    int b = blockIdx.y;                        // batch
    if (j >= INPUT_DIM) return;
    float mx = fmaxf(__uint_as_float(*maxbits), 1e-12f);
    float xs = __fmul_rn(__fdiv_rn(x[b * INPUT_DIM + j], mx), 16.0f);
    int kc = j >> 5;
    int lane = (b & 31) | (((j >> 4) & 1) << 5);
    size_t base = (((size_t)(kc * MB_CNT + (b >> 5)) * 64 + lane) << 4) + (j & 15);
    float v = 0.0f;
    int cnt = 0;
    #pragma unroll
    for (int t = 0; t < T_STEPS; ++t) {
        v = __fadd_rn(__fmul_rn(v, 0.99f), xs);
        int s = (v >= 0.5f) ? 1 : 0;
        cnt += s;
        v = s ? 0.0f : v;
        AF1[base + (size_t)t * 2048] = (uint8_t)s;
    }
    out0[b * INPUT_DIM + j] = (float)cnt / 30.0f;
}

// ---------------- W -> 4 digit planes in MFMA B-fragment order -------------
// q = round(W * scale); 4 signed base-256 digits; per-elem err <= 1/(2*scale).
// BF[nb][kc][d][lane][16]; rows k >= Krows are zero (gemm1 K padding).
__global__ __launch_bounds__(256) void digitize_kernel(const float* __restrict__ W,
                                                       int8_t* __restrict__ BF,
                                                       int Krows, int KC, double scale) {
    __shared__ float tile[32][33];
    const int nb = blockIdx.x, kc = blockIdx.y;
    const int tid = threadIdx.x;
    {
        int r  = tid >> 3;
        int c4 = (tid & 7) << 2;
        int k  = kc * 32 + r;
        float4 w4 = make_float4(0.f, 0.f, 0.f, 0.f);
        if (k < Krows)
            w4 = *(const float4*)&W[(size_t)k * HIDDEN + nb * 32 + c4];
        tile[r][c4]     = w4.x;
        tile[r][c4 + 1] = w4.y;
        tile[r][c4 + 2] = w4.z;
        tile[r][c4 + 3] = w4.w;
    }
    __syncthreads();
    const int d    = tid >> 6;        // wave -> digit plane
    const int lane = tid & 63;
    const int nl   = lane & 31;
    const int kh   = (lane >> 5) << 4;
    char dig[16];
    #pragma unroll
    for (int jj = 0; jj < 16; ++jj) {
        double w = (double)tile[kh + jj][nl];
        long long q = __double2ll_rn(w * scale);
        int dd = 0;
        #pragma unroll
        for (int dd_i = 0; dd_i <= 3; ++dd_i) {
            dd = (int)(((q + 128) & 255) - 128);
            q = (q - (long long)dd) >> 8;
            if (dd_i == d) break;
        }
        dig[jj] = (char)dd;
    }
    *(int4*)&BF[((((size_t)nb * KC + kc) * NDIG + d) << 10) + (lane << 4)] =
        *(int4*)&dig[0];
}

// ---------------- exact i8-digit streaming GEMM (both layers) --------------
// C(1920 x 4096 f64) = A(binary) @ W, 4 digit planes. R6: B-only LDS ring-4,
// A direct global->VGPR with 1-iter register prefetch.
//
// R5 post-mortem: ring-4 + 1 barrier/iter got 122.7->110.3us, MfmaUtil 54.5.
// Remaining binder = LDS BW: reads 48KB + gload-writes 24KB = 72KB/CU/iter
// = ~643 cyc @112 B/cyc > 585 cyc MFMA demand. Fix: A (2KB/wave/chunk, 4KB
// unique/block, L1-friendly, shared by 2 waves) bypasses LDS entirely. LDS
// now carries only B: 16KB write + 32KB read = 48KB/CU/iter = 429 cyc < 585.
//
// A-prefetch correctness chain (in-order vmcnt retirement): per iter k the
// issue order is [A(k+1) loads, stage(k+3)]. The compiler MUST insert a
// vmcnt wait for A(k-1) before MFMA(k-1); A(k-1) was issued AFTER stage(k)
// (iter k-2 order), so that wait retires stage(k) as a side effect. Hence
// at barrier(k) stage(k) is already retired and the manual vmcnt(WN) is a
// pass-through upper bound. WN per iter (outstanding = s(k+1),A(k),s(k+2)):
//   iter 0: queue A(0),s0,s1,s2 -> vmcnt(4) retires A(0)+s0.
//   iter 1: queue s1,s2,A(1),s3 -> vmcnt(6) retires s1.
//   steady: 6 outstanding -> vmcnt(6) vacuous (s(k) retired via A-wait).
//   KC=128 tail (124..127): 6,6,4,2.  KC=25 tail (20..24): 6,6,6,4,2.
// Buffer reuse: stage(k+3)->buf (k+3)&3, last read at iter k-1; every wave
// passed barrier(k) only after MFMA(k-1) whose lgkm waits retired those
// reads -> no write-before-read race (same argument as R5, which passed).
#define MFMA_GRP(A0, A1, B0, B1, B2, B3)                                        \
    acc[0][0] = __builtin_amdgcn_mfma_i32_32x32x32_i8(A0, B0, acc[0][0], 0, 0, 0); \
    acc[1][0] = __builtin_amdgcn_mfma_i32_32x32x32_i8(A1, B0, acc[1][0], 0, 0, 0); \
    acc[0][1] = __builtin_amdgcn_mfma_i32_32x32x32_i8(A0, B1, acc[0][1], 0, 0, 0); \
    acc[1][1] = __builtin_amdgcn_mfma_i32_32x32x32_i8(A1, B1, acc[1][1], 0, 0, 0); \
    acc[0][2] = __builtin_amdgcn_mfma_i32_32x32x32_i8(A0, B2, acc[0][2], 0, 0, 0); \
    acc[1][2] = __builtin_amdgcn_mfma_i32_32x32x32_i8(A1, B2, acc[1][2], 0, 0, 0); \
    acc[0][3] = __builtin_amdgcn_mfma_i32_32x32x32_i8(A0, B3, acc[0][3], 0, 0, 0); \
    acc[1][3] = __builtin_amdgcn_mfma_i32_32x32x32_i8(A1, B3, acc[1][3], 0, 0, 0)

__device__ __forceinline__ void gload16(const int8_t* g, int8_t* l) {
    __builtin_amdgcn_global_load_lds(
        (const __attribute__((address_space(1))) void*)g,
        (__attribute__((address_space(3))) void*)l, 16, 0, 0);
}

// stage chunk KCV's B (2 panels x 4KB) into lds[BUF]: 2 gloads per thread.
// LDS dest is wave-uniform base (+ lane*16 added by HW); global src per-lane.
#define STAGE(BUF, KCV)                                                          \
    do {                                                                         \
        gload16(gB0 + (size_t)(KCV) * bstride, &lds[BUF][       (wave << 10)]);  \
        gload16(gB1 + (size_t)(KCV) * bstride, &lds[BUF][4096 + (wave << 10)]);  \
    } while (0)

// one K-chunk: fence, manual vmcnt + rendezvous, fence, read B frags from
// LDS + prefetch A(KCV+1) into AN regs, fence, stage B(KCV+3), MFMA with
// AC regs (loaded last iter; compiler inserts the vmcnt/lgkm data waits).
#define ITER(S, WN, DOSTAGE, DOA, KCV, AC0, AC1, AN0, AN1)                      \
    do {                                                                         \
        __builtin_amdgcn_sched_barrier(0);                                       \
        asm volatile("s_waitcnt vmcnt(" #WN ")\n\ts_barrier" ::: "memory");      \
        __builtin_amdgcn_sched_barrier(0);                                       \
        v4i b0 = *(const v4i*)&lds[S][((wave & 1) << 12) +        (lane << 4)];  \
        v4i b1 = *(const v4i*)&lds[S][((wave & 1) << 12) + 1024 + (lane << 4)];  \
        v4i b2 = *(const v4i*)&lds[S][((wave & 1) << 12) + 2048 + (lane << 4)];  \
        v4i b3 = *(const v4i*)&lds[S][((wave & 1) << 12) + 3072 + (lane << 4)];  \
        if (DOA) {                                                               \
            AN0 = *(const v4i*)ap; AN1 = *(const v4i*)(ap + 1024);               \
            ap += astride;                                                       \
        }                                                                        \
        __builtin_amdgcn_sched_barrier(0);                                       \
        if (DOSTAGE) { STAGE((S + 3) & 3, (KCV) + 3); }                          \
        MFMA_GRP(AC0, AC1, b0, b1, b2, b3);                                      \
    } while (0)

template <int KC>
__global__ __launch_bounds__(256, 2) void gemm_i8_kernel(const int8_t* __restrict__ AF,
                                                         const int8_t* __restrict__ BF,
                                                         double* __restrict__ C,
                                                         double scale) {
    __shared__ int8_t lds[4][8192];
    const int tid  = threadIdx.x;
    const int wave = tid >> 6, lane = tid & 63;
    const int i  = blockIdx.x;
    // phase-grouped XCD mapping (R3): two dispatch phases of 480; per phase
    // each XCD owns 4 by-windows = 4MB of B (L2-resident).
    const int p  = (i >= 480) ? 1 : 0;
    const int j  = i - p * 480;
    const int bx = j >> 5;                                   // 0..14
    const int by = p * 32 + ((j & 7) << 2) + ((j >> 3) & 3); // 0..63
    const int nb0 = by * 2;
    const int msb = (wave >> 1) * 2;
    const int mb0 = bx * 4 + msb;

    const int astride = MB_CNT * 1024;      // 61440 B per k-chunk in AF
    const int bstride = NDIG * 1024;        // 4096  B per k-chunk in BF panel
    // A: per-wave direct loads (2 frags x 1KB per chunk)
    const int8_t* ap = AF + (((size_t)mb0 * 64 + lane) << 4);
    // B: per-thread 16B staging sources (tid*16 = wave*1024 + lane*16)
    const int8_t* gB0 = BF + (((size_t)nb0 * KC * NDIG) << 10) + tid * 16;
    const int8_t* gB1 = gB0 + ((size_t)KC * NDIG << 10);

    v16i acc[2][4] = {};
    v4i ae0, ae1, ao0, ao1;

    // prologue: A(0) first (so its pre-MFMA(0) wait keeps stages in flight),
    // then B stages for chunks 0..2.
    ae0 = *(const v4i*)ap; ae1 = *(const v4i*)(ap + 1024); ap += astride;
    STAGE(0, 0);
    STAGE(1, 1);
    STAGE(2, 2);

    ITER(0, 4, 1, 1, 0, ae0, ae1, ao0, ao1);   // first: retire A(0)+s0
    ITER(1, 6, 1, 1, 1, ao0, ao1, ae0, ae1);
    ITER(2, 6, 1, 1, 2, ae0, ae1, ao0, ao1);
    ITER(3, 6, 1, 1, 3, ao0, ao1, ae0, ae1);

    constexpr int KCM = ((KC - 4) / 4) * 4; // 124 for KC=128, 20 for KC=25
    for (int kc = 4; kc < KCM; kc += 4) {
        ITER(0, 6, 1, 1, kc,     ae0, ae1, ao0, ao1);
        ITER(1, 6, 1, 1, kc + 1, ao0, ao1, ae0, ae1);
        ITER(2, 6, 1, 1, kc + 2, ae0, ae1, ao0, ao1);
        ITER(3, 6, 1, 1, kc + 3, ao0, ao1, ae0, ae1);
    }
    if constexpr ((KC & 3) == 0) {          // KC=128 tail: 124..127
        ITER(0, 6, 1, 1, KCM,     ae0, ae1, ao0, ao1);  // stage 127
        ITER(1, 6, 0, 1, KCM + 1, ao0, ao1, ae0, ae1);
        ITER(2, 4, 0, 1, KCM + 2, ae0, ae1, ao0, ao1);
        ITER(3, 2, 0, 0, KCM + 3, ao0, ao1, ae0, ae1);
    } else {                                // KC=25 tail: 20..24
        ITER(0, 6, 1, 1, KCM,     ae0, ae1, ao0, ao1);  // stage 23
        ITER(1, 6, 1, 1, KCM + 1, ao0, ao1, ae0, ae1);  // stage 24
        ITER(2, 6, 0, 1, KCM + 2, ae0, ae1, ao0, ao1);
        ITER(3, 4, 0, 1, KCM + 3, ao0, ao1, ae0, ae1);
        ITER(0, 2, 0, 0, KCM + 4, ae0, ae1, ao0, ao1);
    }

    // epilogue: C/D layout col=lane&31, row=(r&3)+8*(r>>2)+4*(lane>>5)
    const int col = lane & 31;
    const int rb  = (lane >> 5) << 2;
    const int n_g = by * 64 + (wave & 1) * 32 + col;
    #pragma unroll
    for (int s = 0; s < 2; ++s) {
        const int m_base = bx * 128 + (msb + s) * 32;
        #pragma unroll
        for (int r = 0; r < 16; ++r) {
            int row = (r & 3) + 8 * (r >> 2) + rb;
            long long v = 0;
            #pragma unroll
            for (int d = 3; d >= 0; --d) v = (v << 8) + (long long)acc[s][d][r];
            C[(size_t)(m_base + row) * HIDDEN + n_g] = (double)v * scale;
        }
    }
}

// ---------------- layer 1 LIF: f64 currents, spikes -> A-fragments ---------
__global__ __launch_bounds__(256) void lif1_kernel(const double* __restrict__ CUR,
                                                   uint8_t* __restrict__ AF,
                                                   float* __restrict__ out1) {
    int e = blockIdx.x * 256 + threadIdx.x;
    int b = e >> 12;
    int j = e & 4095;
    int kc = j >> 5;
    int lane = (b & 31) | (((j >> 4) & 1) << 5);
    size_t base = (((size_t)(kc * MB_CNT + (b >> 5)) * 64 + lane) << 4) + (j & 15);
    double v = 0.0;
    int cnt = 0;
    #pragma unroll
    for (int t = 0; t < T_STEPS; ++t) {
        double cur = CUR[(size_t)t * N1 + e];
        v = __dadd_rn(__dmul_rn(v, 0.99), cur);
        int s = (v >= 0.5) ? 1 : 0;
        cnt += s;
        v = s ? 0.0 : v;
        AF[base + (size_t)t * 2048] = (uint8_t)s;
    }
    out1[e] = (float)cnt / 30.0f;
}

// ---------------- layer 2 LIF in fp64 (unchanged, passing) -----------------
__global__ __launch_bounds__(256) void lif2_kernel(const double* __restrict__ CUR,
                                                   float* __restrict__ out2) {
    int e = blockIdx.x * 256 + threadIdx.x;
    double v = 0.0;
    int cnt = 0;
    #pragma unroll
    for (int t = 0; t < T_STEPS; ++t) {
        double cur = CUR[(size_t)t * N1 + e];
        v = __dadd_rn(__dmul_rn(v, 0.99), cur);
        int s = (v >= 0.5) ? 1 : 0;
        cnt += s;
        v = s ? 0.0 : v;
    }
    out2[e] = (float)cnt / 30.0f;
}

extern "C" void kernel_launch(void* const* d_in, const int* in_sizes, int n_in,
                              void* d_out, int out_size, void* d_ws, size_t ws_size,
                              hipStream_t stream) {
    const float* x  = (const float*)d_in[0];
    const float* W1 = (const float*)d_in[1];   // 784 x 4096
    const float* W2 = (const float*)d_in[2];   // 4096 x 4096
    float* out = (float*)d_out;
    char*  ws  = (char*)d_ws;

    // workspace (~153 MB):
    // [maxbits 256B][AF1 1.54MB][BF1 12.8MB][AF2 7.86MB][BF2 64MB][CURd 62.9MB]
    const size_t AF1_SZ = (size_t)KC1 * MB_CNT * 1024;           // 1,536,000
    const size_t BF1_SZ = (size_t)128 * KC1 * NDIG * 1024;       // 12.8 MB
    const size_t AF2_SZ = (size_t)KC2 * MB_CNT * 1024;           // 7.86 MB
    const size_t BF2_SZ = (size_t)128 * KC2 * NDIG * 1024;       // 64 MB
    unsigned* maxbits = (unsigned*)ws;
    uint8_t*  AF1 = (uint8_t*)(ws + 256);
    int8_t*   BF1 = (int8_t*)(AF1 + AF1_SZ);
    uint8_t*  AF2 = (uint8_t*)(BF1 + BF1_SZ);
    int8_t*   BF2 = (int8_t*)(AF2 + AF2_SZ);
    double*   CURd = (double*)((char*)BF2 + BF2_SZ);

    float* out0 = out;
    float* out1 = out + N0;
    float* out2 = out + N0 + N1;

    hipMemsetAsync(maxbits, 0, 4, stream);
    hipMemsetAsync(AF1, 0, AF1_SZ, stream);   // K-padding rows 784..799 stay 0
    max_kernel <<<(N0 + 255) / 256, 256, 0, stream>>>(x, maxbits);
    lif0_kernel<<<dim3(4, BATCH), 256, 0, stream>>>(x, maxbits, AF1, out0);
    digitize_kernel<<<dim3(128, KC1), 256, 0, stream>>>(W1, BF1, INPUT_DIM, KC1,
                                                        4294967296.0);      // 2^32
    digitize_kernel<<<dim3(128, KC2), 256, 0, stream>>>(W2, BF2, HIDDEN, KC2,
                                                        8589934592.0);      // 2^33
    gemm_i8_kernel<KC1><<<960, 256, 0, stream>>>((const int8_t*)AF1, BF1, CURd,
                                                 2.3283064365386963e-10);   // 2^-32
    lif1_kernel<<<N1 / 256, 256, 0, stream>>>(CURd, AF2, out1);
    gemm_i8_kernel<KC2><<<960, 256, 0, stream>>>((const int8_t*)AF2, BF2, CURd,
                                                 1.1641532182693481e-10);   // 2^-33
    lif2_kernel<<<N1 / 256, 256, 0, stream>>>(CURd, out2);
}

// Round 7
// 304.051 us; speedup vs baseline: 1.0473x; 1.0473x over previous
//
#include <hip/hip_runtime.h>
#include <cstdint>
#include <cstddef>

#define INPUT_DIM 784
#define HIDDEN    4096
#define BATCH     64
#define T_STEPS   30
#define N0 (BATCH*INPUT_DIM)   // 50176
#define N1 (BATCH*HIDDEN)      // 262144
#define M_ROWS (T_STEPS*BATCH) // 1920
#define NDIG 4
#define MB_CNT (M_ROWS/32)     // 60
#define KC1 25                 // gemm1 k-chunks (784 padded to 800)
#define KC2 128                // gemm2 k-chunks

typedef int v4i  __attribute__((ext_vector_type(4)));
typedef int v16i __attribute__((ext_vector_type(16)));

// ---------------- max(x) reduction (unchanged, passing) --------------------
__global__ __launch_bounds__(256) void max_kernel(const float* __restrict__ x,
                                                  unsigned* __restrict__ maxbits) {
    int i = blockIdx.x * 256 + threadIdx.x;
    float v = (i < N0) ? x[i] : 0.0f;
    #pragma unroll
    for (int off = 32; off > 0; off >>= 1)
        v = fmaxf(v, __shfl_down(v, off, 64));
    __shared__ float sm[4];
    int lane = threadIdx.x & 63;
    int wv   = threadIdx.x >> 6;
    if (lane == 0) sm[wv] = v;
    __syncthreads();
    if (threadIdx.x == 0) {
        float m = fmaxf(fmaxf(sm[0], sm[1]), fmaxf(sm[2], sm[3]));
        atomicMax(maxbits, __float_as_uint(m));
    }
}

// ---------------- layer 0 LIF: same math (passing), spikes -> A-fragments --
// AF1[kc][mb][lane][16], lane=(b&31)|(((j>>4)&1)<<5), mb=2t+(b>>5), byte=j&15.
__global__ __launch_bounds__(256) void lif0_kernel(const float* __restrict__ x,
                                                   const unsigned* __restrict__ maxbits,
                                                   uint8_t* __restrict__ AF1,
                                                   float* __restrict__ out0) {
    int j = blockIdx.x * 256 + threadIdx.x;   // input-dim index
    int b = blockIdx.y;                        // batch
    if (j >= INPUT_DIM) return;
    float mx = fmaxf(__uint_as_float(*maxbits), 1e-12f);
    float xs = __fmul_rn(__fdiv_rn(x[b * INPUT_DIM + j], mx), 16.0f);
    int kc = j >> 5;
    int lane = (b & 31) | (((j >> 4) & 1) << 5);
    size_t base = (((size_t)(kc * MB_CNT + (b >> 5)) * 64 + lane) << 4) + (j & 15);
    float v = 0.0f;
    int cnt = 0;
    #pragma unroll
    for (int t = 0; t < T_STEPS; ++t) {
        v = __fadd_rn(__fmul_rn(v, 0.99f), xs);
        int s = (v >= 0.5f) ? 1 : 0;
        cnt += s;
        v = s ? 0.0f : v;
        AF1[base + (size_t)t * 2048] = (uint8_t)s;
    }
    out0[b * INPUT_DIM + j] = (float)cnt / 30.0f;
}

// ---------------- W -> 4 digit planes in MFMA B-fragment order -------------
// q = round(W * scale); 4 signed base-256 digits; per-elem err <= 1/(2*scale).
// BF[nb][kc][d][lane][16]; rows k >= Krows are zero (gemm1 K padding).
__global__ __launch_bounds__(256) void digitize_kernel(const float* __restrict__ W,
                                                       int8_t* __restrict__ BF,
                                                       int Krows, int KC, double scale) {
    __shared__ float tile[32][33];
    const int nb = blockIdx.x, kc = blockIdx.y;
    const int tid = threadIdx.x;
    {
        int r  = tid >> 3;
        int c4 = (tid & 7) << 2;
        int k  = kc * 32 + r;
        float4 w4 = make_float4(0.f, 0.f, 0.f, 0.f);
        if (k < Krows)
            w4 = *(const float4*)&W[(size_t)k * HIDDEN + nb * 32 + c4];
        tile[r][c4]     = w4.x;
        tile[r][c4 + 1] = w4.y;
        tile[r][c4 + 2] = w4.z;
        tile[r][c4 + 3] = w4.w;
    }
    __syncthreads();
    const int d    = tid >> 6;        // wave -> digit plane
    const int lane = tid & 63;
    const int nl   = lane & 31;
    const int kh   = (lane >> 5) << 4;
    char dig[16];
    #pragma unroll
    for (int jj = 0; jj < 16; ++jj) {
        double w = (double)tile[kh + jj][nl];
        long long q = __double2ll_rn(w * scale);
        int dd = 0;
        #pragma unroll
        for (int dd_i = 0; dd_i <= 3; ++dd_i) {
            dd = (int)(((q + 128) & 255) - 128);
            q = (q - (long long)dd) >> 8;
            if (dd_i == d) break;
        }
        dig[jj] = (char)dd;
    }
    *(int4*)&BF[((((size_t)nb * KC + kc) * NDIG + d) << 10) + (lane << 4)] =
        *(int4*)&dig[0];
}

// ---------------- exact i8-digit streaming GEMM (both layers) --------------
// C(1920 x 4096 f64) = A(binary) @ W, 4 digit planes. R7: R5's ring-4 LDS
// (A+B staged, 1 barrier/iter) + REGISTER FRAGMENT PIPELINE.
//
// R6 post-mortem: A-direct-to-VGPR regressed to 136.7us (re-entered the
// VMEM-return-path regime R4 escaped). Reverted to R5 structure.
// R5 residual analysis: wall 1103 cyc/iter vs MFMA 584 + LDS 643 -- the two
// pipes SERIALIZE because MFMA(k) depends on ds_reads issued the same iter
// (lockstep read-then-compute). R7 breaks the dependency: ds_reads at iter
// k fetch fragments for chunk k+1; MFMA(k) uses regs read at iter k-1.
// Reads drain under the MFMA cluster (compiler fine-grained lgkmcnt) ->
// wall ~ max(MFMA, LDS) instead of sum.
//
// Safety (same invariants as R5, which passed):
//  - reads at iter k hit buf (k+1)&3: each wave retired its own stage(k+1)
//    (issued iter k-2) via vmcnt(3) before barrier(k) -> data landed.
//  - stage at iter k writes buf (k+3)&3, whose last reads (frags k-1, iter
//    k-2) were lgkm-retired before MFMA(k-1) at iter k-1, which precedes
//    barrier(k) for every wave -> no write-before-read.
//  - reads at iter k write frag set (k+1)&1; MFMA(k) uses set k&1 -> no WAR.
// vmcnt ledger (3 gloads/stage, in-order): at barrier(k) in flight =
// {stage(k+1), stage(k+2)}; retire k+1 -> vmcnt(3). Prep: {0,1,2} retire 0
// -> vmcnt(6). Tails: KC=128 iters 124,125 -> 3, 126 -> 0; KC=25 iters
// 20,21,22 -> 3, 23 -> 0. Final iter: MFMA only, no barrier.
#define MFMA_GRP(A0, A1, B0, B1, B2, B3)                                        \
    acc[0][0] = __builtin_amdgcn_mfma_i32_32x32x32_i8(A0, B0, acc[0][0], 0, 0, 0); \
    acc[1][0] = __builtin_amdgcn_mfma_i32_32x32x32_i8(A1, B0, acc[1][0], 0, 0, 0); \
    acc[0][1] = __builtin_amdgcn_mfma_i32_32x32x32_i8(A0, B1, acc[0][1], 0, 0, 0); \
    acc[1][1] = __builtin_amdgcn_mfma_i32_32x32x32_i8(A1, B1, acc[1][1], 0, 0, 0); \
    acc[0][2] = __builtin_amdgcn_mfma_i32_32x32x32_i8(A0, B2, acc[0][2], 0, 0, 0); \
    acc[1][2] = __builtin_amdgcn_mfma_i32_32x32x32_i8(A1, B2, acc[1][2], 0, 0, 0); \
    acc[0][3] = __builtin_amdgcn_mfma_i32_32x32x32_i8(A0, B3, acc[0][3], 0, 0, 0); \
    acc[1][3] = __builtin_amdgcn_mfma_i32_32x32x32_i8(A1, B3, acc[1][3], 0, 0, 0)

__device__ __forceinline__ void gload16(const int8_t* g, int8_t* l) {
    __builtin_amdgcn_global_load_lds(
        (const __attribute__((address_space(1))) void*)g,
        (__attribute__((address_space(3))) void*)l, 16, 0, 0);
}

// stage next chunk (running pointers) into lds[BUF]: A 4KB + B 2x4KB.
// LDS dest is wave-uniform base (+ lane*16 added by HW); global src per-lane.
#define STAGE(BUF)                                                               \
    do {                                                                         \
        gload16(spA,  &lds[BUF][       (wave << 10)]);                           \
        gload16(spB0, &lds[BUF][4096 + (wave << 10)]);                           \
        gload16(spB1, &lds[BUF][8192 + (wave << 10)]);                           \
        spA += astride; spB0 += bstride; spB1 += bstride;                        \
    } while (0)

// one K-chunk: fence, counted vmcnt + rendezvous, fence, read NEXT chunk's
// fragments (set N*) from buf RB, stage chunk+3 into buf SB, MFMA on the
// CURRENT fragments (set C*, read last iter -- no dependency on this iter's
// ds_reads, so they drain under the MFMA cluster).
#define ITER(WN, RB, DOSTAGE, SB, CA0, CA1, CB0, CB1, CB2, CB3,                  \
             NA0, NA1, NB0, NB1, NB2, NB3)                                       \
    do {                                                                         \
        __builtin_amdgcn_sched_barrier(0);                                       \
        asm volatile("s_waitcnt vmcnt(" #WN ")\n\ts_barrier" ::: "memory");      \
        __builtin_amdgcn_sched_barrier(0);                                       \
        NA0 = *(const v4i*)&lds[RB][ msb      * 1024 + (lane << 4)];             \
        NA1 = *(const v4i*)&lds[RB][(msb + 1) * 1024 + (lane << 4)];             \
        NB0 = *(const v4i*)&lds[RB][4096 + ((wave & 1) << 12) +        (lane << 4)]; \
        NB1 = *(const v4i*)&lds[RB][4096 + ((wave & 1) << 12) + 1024 + (lane << 4)]; \
        NB2 = *(const v4i*)&lds[RB][4096 + ((wave & 1) << 12) + 2048 + (lane << 4)]; \
        NB3 = *(const v4i*)&lds[RB][4096 + ((wave & 1) << 12) + 3072 + (lane << 4)]; \
        if (DOSTAGE) { STAGE(SB); }                                              \
        MFMA_GRP(CA0, CA1, CB0, CB1, CB2, CB3);                                  \
    } while (0)

template <int KC>
__global__ __launch_bounds__(256, 2) void gemm_i8_kernel(const int8_t* __restrict__ AF,
                                                         const int8_t* __restrict__ BF,
                                                         double* __restrict__ C,
                                                         double scale) {
    __shared__ int8_t lds[4][12288];
    const int tid  = threadIdx.x;
    const int wave = tid >> 6, lane = tid & 63;
    const int i  = blockIdx.x;
    // phase-grouped XCD mapping (R3): two dispatch phases of 480; per phase
    // each XCD owns 4 by-windows = 4MB of B (L2-resident).
    const int p  = (i >= 480) ? 1 : 0;
    const int j  = i - p * 480;
    const int bx = j >> 5;                                   // 0..14
    const int by = p * 32 + ((j & 7) << 2) + ((j >> 3) & 3); // 0..63
    const int nb0 = by * 2;
    const int msb = (wave >> 1) * 2;

    const int astride = MB_CNT * 1024;      // 61440 B per k-chunk in AF
    const int bstride = NDIG * 1024;        // 4096  B per k-chunk in BF panel
    // per-thread 16B staging sources (tid*16 = wave*1024 + lane*16)
    const int8_t* spA  = AF + (((size_t)(bx * 4) * 64) << 4) + tid * 16;
    const int8_t* spB0 = BF + (((size_t)nb0 * KC * NDIG) << 10) + tid * 16;
    const int8_t* spB1 = spB0 + ((size_t)KC * NDIG << 10);

    v16i acc[2][4] = {};
    v4i eA0, eA1, eB0, eB1, eB2, eB3;       // frag set E (even chunks)
    v4i oA0, oA1, oB0, oB1, oB2, oB3;       // frag set O (odd chunks)

    STAGE(0);                               // chunk 0 -> buf 0
    STAGE(1);                               // chunk 1 -> buf 1
    STAGE(2);                               // chunk 2 -> buf 2

    // prep: land chunk 0, read frags[0] into set E. No MFMA yet.
    __builtin_amdgcn_sched_barrier(0);
    asm volatile("s_waitcnt vmcnt(6)\n\ts_barrier" ::: "memory");
    __builtin_amdgcn_sched_barrier(0);
    eA0 = *(const v4i*)&lds[0][ msb      * 1024 + (lane << 4)];
    eA1 = *(const v4i*)&lds[0][(msb + 1) * 1024 + (lane << 4)];
    eB0 = *(const v4i*)&lds[0][4096 + ((wave & 1) << 12) +        (lane << 4)];
    eB1 = *(const v4i*)&lds[0][4096 + ((wave & 1) << 12) + 1024 + (lane << 4)];
    eB2 = *(const v4i*)&lds[0][4096 + ((wave & 1) << 12) + 2048 + (lane << 4)];
    eB3 = *(const v4i*)&lds[0][4096 + ((wave & 1) << 12) + 3072 + (lane << 4)];

    // main: iter k = MFMA(k) on set k&1, read frags[k+1] from buf (k+1)&3
    // into set (k+1)&1, stage chunk k+3 into buf (k+3)&3.
    constexpr int KCM = ((KC - 4) / 4) * 4; // 124 for KC=128, 20 for KC=25
    for (int g = 0; g < KCM / 4; ++g) {
        ITER(3, 1, 1, 3, eA0, eA1, eB0, eB1, eB2, eB3, oA0, oA1, oB0, oB1, oB2, oB3);
        ITER(3, 2, 1, 0, oA0, oA1, oB0, oB1, oB2, oB3, eA0, eA1, eB0, eB1, eB2, eB3);
        ITER(3, 3, 1, 1, eA0, eA1, eB0, eB1, eB2, eB3, oA0, oA1, oB0, oB1, oB2, oB3);
        ITER(3, 0, 1, 2, oA0, oA1, oB0, oB1, oB2, oB3, eA0, eA1, eB0, eB1, eB2, eB3);
    }
    if constexpr ((KC & 3) == 0) {          // KC=128 tail: iters 124..127
        ITER(3, 1, 1, 3, eA0, eA1, eB0, eB1, eB2, eB3, oA0, oA1, oB0, oB1, oB2, oB3); // stage 127
        ITER(3, 2, 0, 0, oA0, oA1, oB0, oB1, oB2, oB3, eA0, eA1, eB0, eB1, eB2, eB3);
        ITER(0, 3, 0, 0, eA0, eA1, eB0, eB1, eB2, eB3, oA0, oA1, oB0, oB1, oB2, oB3);
        MFMA_GRP(oA0, oA1, oB0, oB1, oB2, oB3);                                       // iter 127
    } else {                                // KC=25 tail: iters 20..24
        ITER(3, 1, 1, 3, eA0, eA1, eB0, eB1, eB2, eB3, oA0, oA1, oB0, oB1, oB2, oB3); // stage 23
        ITER(3, 2, 1, 0, oA0, oA1, oB0, oB1, oB2, oB3, eA0, eA1, eB0, eB1, eB2, eB3); // stage 24
        ITER(3, 3, 0, 0, eA0, eA1, eB0, eB1, eB2, eB3, oA0, oA1, oB0, oB1, oB2, oB3);
        ITER(0, 0, 0, 0, oA0, oA1, oB0, oB1, oB2, oB3, eA0, eA1, eB0, eB1, eB2, eB3);
        MFMA_GRP(eA0, eA1, eB0, eB1, eB2, eB3);                                       // iter 24
    }

    // epilogue: C/D layout col=lane&31, row=(r&3)+8*(r>>2)+4*(lane>>5)
    const int col = lane & 31;
    const int rb  = (lane >> 5) << 2;
    const int n_g = by * 64 + (wave & 1) * 32 + col;
    #pragma unroll
    for (int s = 0; s < 2; ++s) {
        const int m_base = bx * 128 + (msb + s) * 32;
        #pragma unroll
        for (int r = 0; r < 16; ++r) {
            int row = (r & 3) + 8 * (r >> 2) + rb;
            long long v = 0;
            #pragma unroll
            for (int d = 3; d >= 0; --d) v = (v << 8) + (long long)acc[s][d][r];
            C[(size_t)(m_base + row) * HIDDEN + n_g] = (double)v * scale;
        }
    }
}

// ---------------- layer 1 LIF: f64 currents, spikes -> A-fragments ---------
__global__ __launch_bounds__(256) void lif1_kernel(const double* __restrict__ CUR,
                                                   uint8_t* __restrict__ AF,
                                                   float* __restrict__ out1) {
    int e = blockIdx.x * 256 + threadIdx.x;
    int b = e >> 12;
    int j = e & 4095;
    int kc = j >> 5;
    int lane = (b & 31) | (((j >> 4) & 1) << 5);
    size_t base = (((size_t)(kc * MB_CNT + (b >> 5)) * 64 + lane) << 4) + (j & 15);
    double v = 0.0;
    int cnt = 0;
    #pragma unroll
    for (int t = 0; t < T_STEPS; ++t) {
        double cur = CUR[(size_t)t * N1 + e];
        v = __dadd_rn(__dmul_rn(v, 0.99), cur);
        int s = (v >= 0.5) ? 1 : 0;
        cnt += s;
        v = s ? 0.0 : v;
        AF[base + (size_t)t * 2048] = (uint8_t)s;
    }
    out1[e] = (float)cnt / 30.0f;
}

// ---------------- layer 2 LIF in fp64 (unchanged, passing) -----------------
__global__ __launch_bounds__(256) void lif2_kernel(const double* __restrict__ CUR,
                                                   float* __restrict__ out2) {
    int e = blockIdx.x * 256 + threadIdx.x;
    double v = 0.0;
    int cnt = 0;
    #pragma unroll
    for (int t = 0; t < T_STEPS; ++t) {
        double cur = CUR[(size_t)t * N1 + e];
        v = __dadd_rn(__dmul_rn(v, 0.99), cur);
        int s = (v >= 0.5) ? 1 : 0;
        cnt += s;
        v = s ? 0.0 : v;
    }
    out2[e] = (float)cnt / 30.0f;
}

extern "C" void kernel_launch(void* const* d_in, const int* in_sizes, int n_in,
                              void* d_out, int out_size, void* d_ws, size_t ws_size,
                              hipStream_t stream) {
    const float* x  = (const float*)d_in[0];
    const float* W1 = (const float*)d_in[1];   // 784 x 4096
    const float* W2 = (const float*)d_in[2];   // 4096 x 4096
    float* out = (float*)d_out;
    char*  ws  = (char*)d_ws;

    // workspace (~153 MB):
    // [maxbits 256B][AF1 1.54MB][BF1 12.8MB][AF2 7.86MB][BF2 64MB][CURd 62.9MB]
    const size_t AF1_SZ = (size_t)KC1 * MB_CNT * 1024;           // 1,536,000
    const size_t BF1_SZ = (size_t)128 * KC1 * NDIG * 1024;       // 12.8 MB
    const size_t AF2_SZ = (size_t)KC2 * MB_CNT * 1024;           // 7.86 MB
    const size_t BF2_SZ = (size_t)128 * KC2 * NDIG * 1024;       // 64 MB
    unsigned* maxbits = (unsigned*)ws;
    uint8_t*  AF1 = (uint8_t*)(ws + 256);
    int8_t*   BF1 = (int8_t*)(AF1 + AF1_SZ);
    uint8_t*  AF2 = (uint8_t*)(BF1 + BF1_SZ);
    int8_t*   BF2 = (int8_t*)(AF2 + AF2_SZ);
    double*   CURd = (double*)((char*)BF2 + BF2_SZ);

    float* out0 = out;
    float* out1 = out + N0;
    float* out2 = out + N0 + N1;

    hipMemsetAsync(maxbits, 0, 4, stream);
    hipMemsetAsync(AF1, 0, AF1_SZ, stream);   // K-padding rows 784..799 stay 0
    max_kernel <<<(N0 + 255) / 256, 256, 0, stream>>>(x, maxbits);
    lif0_kernel<<<dim3(4, BATCH), 256, 0, stream>>>(x, maxbits, AF1, out0);
    digitize_kernel<<<dim3(128, KC1), 256, 0, stream>>>(W1, BF1, INPUT_DIM, KC1,
                                                        4294967296.0);      // 2^32
    digitize_kernel<<<dim3(128, KC2), 256, 0, stream>>>(W2, BF2, HIDDEN, KC2,
                                                        8589934592.0);      // 2^33
    gemm_i8_kernel<KC1><<<960, 256, 0, stream>>>((const int8_t*)AF1, BF1, CURd,
                                                 2.3283064365386963e-10);   // 2^-32
    lif1_kernel<<<N1 / 256, 256, 0, stream>>>(CURd, AF2, out1);
    gemm_i8_kernel<KC2><<<960, 256, 0, stream>>>((const int8_t*)AF2, BF2, CURd,
                                                 1.1641532182693481e-10);   // 2^-33
    lif2_kernel<<<N1 / 256, 256, 0, stream>>>(CURd, out2);
}